// Round 2
// baseline (108.021 us; speedup 1.0000x reference)
//
#include <hip/hip_runtime.h>

// RoPE on x:(4,32,4096,128) fp32, interleaved-pair convention.
// freq_i = 10000^(-2i/128) = exp2(i * C), C = -log2(10000)/64
// pair (X,Y) at d=(2i,2i+1): out = (X*cos - Y*sin, X*sin + Y*cos), ang = s*freq_i.
// Memory-bound: 512 MiB traffic -> target ~85us @ 6.3 TB/s.

__global__ void ROPE_23476291240446_kernel(const float4* __restrict__ x,
                                           float4* __restrict__ out,
                                           int n4) {
    // Each float4 = 2 rotation pairs. 32 float4 per d=128 row.
    const float C = -0.207620505929682f;     // -log2(10000)/64
    const float R = 0.865964323360110f;      // exp2(C) = freq ratio between adjacent i

    int idx = blockIdx.x * blockDim.x + threadIdx.x;
    int stride = gridDim.x * blockDim.x;

    for (int v = idx; v < n4; v += stride) {
        int j = v & 31;                      // float4 index within row -> pairs i0=2j, i1=2j+1
        int s = (v >> 5) & 4095;             // sequence position
        float pos = (float)s;

        float f0 = exp2f((float)(2 * j) * C);   // native v_exp_f32 on gfx950
        float f1 = f0 * R;

        float a0 = pos * f0;
        float a1 = pos * f1;

        float s0, c0, s1, c1;
        __sincosf(a0, &s0, &c0);
        __sincosf(a1, &s1, &c1);

        float4 xv = x[v];
        float4 o;
        o.x = xv.x * c0 - xv.y * s0;
        o.y = xv.x * s0 + xv.y * c0;
        o.z = xv.z * c1 - xv.w * s1;
        o.w = xv.z * s1 + xv.w * c1;
        out[v] = o;
    }
}

extern "C" void kernel_launch(void* const* d_in, const int* in_sizes, int n_in,
                              void* d_out, int out_size, void* d_ws, size_t ws_size,
                              hipStream_t stream) {
    const float* x = (const float*)d_in[0];
    float* out = (float*)d_out;

    int n4 = in_sizes[0] / 4;                // 16,777,216 float4s

    const int block = 256;
    const int grid = 2048;                   // grid-stride, ~8 blocks/CU
    ROPE_23476291240446_kernel<<<grid, block, 0, stream>>>(
        (const float4*)x, (float4*)out, n4);
}